// Round 1
// baseline (741.700 us; speedup 1.0000x reference)
//
#include <hip/hip_runtime.h>

static constexpr float kBnEps = 1e-5f;

// ---------------------------------------------------------------------------
// Edge-index format detection: reference dtype is int64, harness doc says
// int32. If storage is int64 (little-endian, values < 2^31), every odd int32
// word is a zero hi-word. Check the first 64 odd words; all-zero => int64.
// ---------------------------------------------------------------------------
__global__ void detect_k(const int* __restrict__ eb, int* __restrict__ flag) {
    int l = threadIdx.x;  // 64 threads
    int v = eb[2 * l + 1];
    unsigned long long m = __ballot(v == 0);
    if (l == 0) flag[0] = (m == ~0ull) ? 1 : 0;
}

__device__ __forceinline__ int edge_src(const int* eb, int is64, int E, int e) {
    return is64 ? eb[2 * e] : eb[e];
}
__device__ __forceinline__ int edge_dst(const int* eb, int is64, int E, int e) {
    return is64 ? eb[2 * E + 2 * e] : eb[E + e];
}

// ---------------------------------------------------------------------------
// Degree histogram (int atomics, deterministic)
// ---------------------------------------------------------------------------
__global__ void count_k(const int* __restrict__ eb, const int* __restrict__ flag,
                        int* __restrict__ cnt, int E) {
    int e = blockIdx.x * blockDim.x + threadIdx.x;
    if (e >= E) return;
    int is64 = flag[0];
    atomicAdd(&cnt[edge_dst(eb, is64, E, e)], 1);
}

// ---------------------------------------------------------------------------
// 3-kernel exclusive scan over N=50000 counts (256/block Hillis-Steele)
// ---------------------------------------------------------------------------
__global__ void scan1_k(const int* __restrict__ cnt, int* __restrict__ offs,
                        int* __restrict__ bsum, int n) {
    __shared__ int s[256];
    int tid = threadIdx.x;
    int i = blockIdx.x * 256 + tid;
    int v = (i < n) ? cnt[i] : 0;
    s[tid] = v;
    __syncthreads();
    for (int d = 1; d < 256; d <<= 1) {
        int t = (tid >= d) ? s[tid - d] : 0;
        __syncthreads();
        s[tid] += t;
        __syncthreads();
    }
    if (i < n) offs[i] = s[tid] - v;  // exclusive within block
    if (tid == 255) bsum[blockIdx.x] = s[255];
}

__global__ void scan2_k(int* __restrict__ bsum, int nb) {
    __shared__ int s[256];
    int tid = threadIdx.x;
    int v = (tid < nb) ? bsum[tid] : 0;
    s[tid] = v;
    __syncthreads();
    for (int d = 1; d < 256; d <<= 1) {
        int t = (tid >= d) ? s[tid - d] : 0;
        __syncthreads();
        s[tid] += t;
        __syncthreads();
    }
    if (tid < nb) bsum[tid] = s[tid] - v;  // exclusive block offsets
}

__global__ void scan3_k(int* __restrict__ offs, const int* __restrict__ bsum,
                        int* __restrict__ cursor, int n, int E) {
    int i = blockIdx.x * 256 + threadIdx.x;
    if (i < n) {
        int o = offs[i] + bsum[i >> 8];
        offs[i] = o;
        cursor[i] = o;
    }
    if (i == 0) offs[n] = E;
}

// ---------------------------------------------------------------------------
// CSR fill: csr[pos] = src for each edge grouped by dst
// ---------------------------------------------------------------------------
__global__ void fill_k(const int* __restrict__ eb, const int* __restrict__ flag,
                       int* __restrict__ cursor, int* __restrict__ csr, int E) {
    int e = blockIdx.x * blockDim.x + threadIdx.x;
    if (e >= E) return;
    int is64 = flag[0];
    int s = edge_src(eb, is64, E, e);
    int d = edge_dst(eb, is64, E, e);
    int pos = atomicAdd(&cursor[d], 1);
    csr[pos] = s;
}

// ---------------------------------------------------------------------------
// Mean aggregation: one wave (64 lanes) per node; lane covers 2 of 128 cols.
// Row reads are 512B contiguous per neighbor; accumulate in registers,
// scale by 1/max(deg,1) on store. Zero fp atomics.
// ---------------------------------------------------------------------------
__global__ void agg_k(const float* __restrict__ X, const int* __restrict__ offs,
                      const int* __restrict__ csr, float* __restrict__ agg, int n) {
    int gt = blockIdx.x * blockDim.x + threadIdx.x;
    int wid = gt >> 6;
    int lane = threadIdx.x & 63;
    if (wid >= n) return;
    int beg = offs[wid], end = offs[wid + 1];
    float a0 = 0.f, a1 = 0.f;
    for (int j = beg; j < end; ++j) {
        int s = csr[j];  // wave-uniform
        const float* xr = X + (size_t)s * 128;
        a0 += xr[lane];
        a1 += xr[lane + 64];
    }
    float inv = 1.0f / fmaxf((float)(end - beg), 1.0f);
    float* ar = agg + (size_t)wid * 128;
    ar[lane] = a0 * inv;
    ar[lane + 64] = a1 * inv;
}

// ---------------------------------------------------------------------------
// Fused SAGE linear:  out = epi( Agg@Wl.T + X@Wr.T + b )
//   epi = identity (layer 2 / heads) or  relu(v * g/sqrt(1+eps) + be)
// Block tile 64 rows x 128 cols, BK=16, thread tile 4x8, 256 threads.
// HAS_AGG=false => plain out = X@Wr.T + b (decoder heads).
// ---------------------------------------------------------------------------
template <bool HAS_AGG, bool BN_RELU>
__global__ __launch_bounds__(256) void gemm_k(
    const float* __restrict__ Agg, const float* __restrict__ X,
    const float* __restrict__ Wl, const float* __restrict__ Wr,
    const float* __restrict__ bias, const float* __restrict__ g,
    const float* __restrict__ be, float* __restrict__ out, int n) {
    __shared__ float sX[64 * 17];
    __shared__ float sA[HAS_AGG ? 64 * 17 : 1];
    __shared__ float sWr[16 * 128];
    __shared__ float sWl[HAS_AGG ? 16 * 128 : 1];

    const int tid = threadIdx.x;
    const int row0 = blockIdx.x * 64;
    const int tx = tid & 15;   // 16 col groups x 8 cols
    const int ty = tid >> 4;   // 16 row groups x 4 rows

    float acc[4][8];
#pragma unroll
    for (int i = 0; i < 4; ++i)
#pragma unroll
        for (int j = 0; j < 8; ++j) acc[i][j] = 0.f;

    for (int k0 = 0; k0 < 128; k0 += 16) {
        // --- A tiles: 64 rows x 16 k, one float4 per thread
        {
            int r = tid >> 2;
            int c4 = (tid & 3) << 2;
            int rg = row0 + r;
            float4 xv = make_float4(0.f, 0.f, 0.f, 0.f);
            float4 av = xv;
            if (rg < n) {
                xv = *reinterpret_cast<const float4*>(X + (size_t)rg * 128 + k0 + c4);
                if (HAS_AGG)
                    av = *reinterpret_cast<const float4*>(Agg + (size_t)rg * 128 + k0 + c4);
            }
            float* px = &sX[r * 17 + c4];
            px[0] = xv.x; px[1] = xv.y; px[2] = xv.z; px[3] = xv.w;
            if (HAS_AGG) {
                float* pa = &sA[r * 17 + c4];
                pa[0] = av.x; pa[1] = av.y; pa[2] = av.z; pa[3] = av.w;
            }
        }
        // --- W tiles: 16 k x 128 cols, stored k-major (transposed load)
#pragma unroll
        for (int i = 0; i < 8; ++i) {
            int idx = tid + i * 256;   // 0..2047
            int kk = idx >> 7, col = idx & 127;
            sWr[kk * 128 + col] = Wr[col * 128 + k0 + kk];
            if (HAS_AGG) sWl[kk * 128 + col] = Wl[col * 128 + k0 + kk];
        }
        __syncthreads();
#pragma unroll
        for (int kk = 0; kk < 16; ++kk) {
            float xr[4], ar[4];
#pragma unroll
            for (int i = 0; i < 4; ++i) {
                xr[i] = sX[(ty * 4 + i) * 17 + kk];
                if (HAS_AGG) ar[i] = sA[(ty * 4 + i) * 17 + kk];
            }
            float wr[8], wl[8];
            {
                float4 w0 = *reinterpret_cast<const float4*>(&sWr[kk * 128 + tx * 8]);
                float4 w1 = *reinterpret_cast<const float4*>(&sWr[kk * 128 + tx * 8 + 4]);
                wr[0] = w0.x; wr[1] = w0.y; wr[2] = w0.z; wr[3] = w0.w;
                wr[4] = w1.x; wr[5] = w1.y; wr[6] = w1.z; wr[7] = w1.w;
            }
            if (HAS_AGG) {
                float4 w0 = *reinterpret_cast<const float4*>(&sWl[kk * 128 + tx * 8]);
                float4 w1 = *reinterpret_cast<const float4*>(&sWl[kk * 128 + tx * 8 + 4]);
                wl[0] = w0.x; wl[1] = w0.y; wl[2] = w0.z; wl[3] = w0.w;
                wl[4] = w1.x; wl[5] = w1.y; wl[6] = w1.z; wl[7] = w1.w;
            }
#pragma unroll
            for (int i = 0; i < 4; ++i)
#pragma unroll
                for (int j = 0; j < 8; ++j) {
                    acc[i][j] += xr[i] * wr[j];
                    if (HAS_AGG) acc[i][j] += ar[i] * wl[j];
                }
        }
        __syncthreads();
    }
    // --- epilogue
#pragma unroll
    for (int i = 0; i < 4; ++i) {
        int rg = row0 + ty * 4 + i;
        if (rg >= n) continue;
        float vout[8];
#pragma unroll
        for (int j = 0; j < 8; ++j) {
            int col = tx * 8 + j;
            float v = acc[i][j] + bias[col];
            if (BN_RELU) {
                float s = g[col] / sqrtf(1.0f + kBnEps);
                v = fmaxf(v * s + be[col], 0.f);
            }
            vout[j] = v;
        }
        float4* po = reinterpret_cast<float4*>(out + (size_t)rg * 128 + tx * 8);
        po[0] = make_float4(vout[0], vout[1], vout[2], vout[3]);
        po[1] = make_float4(vout[4], vout[5], vout[6], vout[7]);
    }
}

// ---------------------------------------------------------------------------
// Tiny head: out[N,7] = h @ dW2.T + db2. One thread per row, W2 in LDS.
// ---------------------------------------------------------------------------
__global__ __launch_bounds__(256) void head2_k(const float* __restrict__ h,
                                               const float* __restrict__ W2,
                                               const float* __restrict__ b2,
                                               float* __restrict__ out, int n) {
    __shared__ float sw[7 * 128];
    __shared__ float sb[7];
    int tid = threadIdx.x;
    for (int i = tid; i < 7 * 128; i += 256) sw[i] = W2[i];
    if (tid < 7) sb[tid] = b2[tid];
    __syncthreads();
    int row = blockIdx.x * 256 + tid;
    if (row >= n) return;
    const float4* hr = reinterpret_cast<const float4*>(h + (size_t)row * 128);
    float acc[7] = {0.f, 0.f, 0.f, 0.f, 0.f, 0.f, 0.f};
    for (int k4 = 0; k4 < 32; ++k4) {
        float4 hv = hr[k4];
#pragma unroll
        for (int c = 0; c < 7; ++c) {
            const float4 wv = *reinterpret_cast<const float4*>(&sw[c * 128 + k4 * 4]);
            acc[c] += hv.x * wv.x + hv.y * wv.y + hv.z * wv.z + hv.w * wv.w;
        }
    }
#pragma unroll
    for (int c = 0; c < 7; ++c) out[(size_t)row * 7 + c] = acc[c] + sb[c];
}

// ---------------------------------------------------------------------------
extern "C" void kernel_launch(void* const* d_in, const int* in_sizes, int n_in,
                              void* d_out, int out_size, void* d_ws, size_t ws_size,
                              hipStream_t stream) {
    const float* x   = (const float*)d_in[0];
    const int*   eb  = (const int*)d_in[1];
    const float* Wl0 = (const float*)d_in[2];
    const float* Wr0 = (const float*)d_in[3];
    const float* b0  = (const float*)d_in[4];
    const float* Wl1 = (const float*)d_in[5];
    const float* Wr1 = (const float*)d_in[6];
    const float* b1  = (const float*)d_in[7];
    const float* Wl2 = (const float*)d_in[8];
    const float* Wr2 = (const float*)d_in[9];
    const float* b2  = (const float*)d_in[10];
    const float* g0  = (const float*)d_in[11];
    const float* be0 = (const float*)d_in[12];
    const float* g1  = (const float*)d_in[13];
    const float* be1 = (const float*)d_in[14];
    const float* dW1 = (const float*)d_in[15];
    const float* db1 = (const float*)d_in[16];
    const float* dW2 = (const float*)d_in[17];
    const float* db2 = (const float*)d_in[18];
    const float* dW3 = (const float*)d_in[19];
    const float* db3 = (const float*)d_in[20];

    const int n = in_sizes[0] / 128;
    const int E = in_sizes[1] / 2;

    // workspace layout (256B aligned)
    char* ws = (char*)d_ws;
    size_t off = 0;
    auto alloc = [&](size_t bytes) -> void* {
        void* p = ws + off;
        off = (off + bytes + 255) & ~(size_t)255;
        return p;
    };
    int*   flag   = (int*)alloc(16);
    int*   cnt    = (int*)alloc((size_t)n * 4);
    int*   offs   = (int*)alloc((size_t)(n + 1) * 4);
    int*   bsum   = (int*)alloc(1024);
    int*   cursor = (int*)alloc((size_t)n * 4);
    int*   csr    = (int*)alloc((size_t)E * 4);
    float* agg    = (float*)alloc((size_t)n * 128 * 4);
    float* h2     = (float*)alloc((size_t)n * 128 * 4);

    float* out0 = (float*)d_out;             // recon1 slot; h0 scratch first
    float* out1 = out0 + (size_t)n * 128;    // recon2 slot
    float* out2 = out1 + (size_t)n * 7;      // recon3 slot; h1 scratch first

    hipMemsetAsync(cnt, 0, (size_t)n * 4, stream);

    const int nbN = (n + 255) / 256;
    const int nbE = (E + 255) / 256;
    const int gemm_grid = (n + 63) / 64;
    const int agg_grid = (n * 64 + 255) / 256;  // one wave per node

    detect_k<<<1, 64, 0, stream>>>(eb, flag);
    count_k<<<nbE, 256, 0, stream>>>(eb, flag, cnt, E);
    scan1_k<<<nbN, 256, 0, stream>>>(cnt, offs, bsum, n);
    scan2_k<<<1, 256, 0, stream>>>(bsum, nbN);
    scan3_k<<<nbN, 256, 0, stream>>>(offs, bsum, cursor, n, E);
    fill_k<<<nbE, 256, 0, stream>>>(eb, flag, cursor, csr, E);

    // layer 0
    agg_k<<<agg_grid, 256, 0, stream>>>(x, offs, csr, agg, n);
    gemm_k<true, true><<<gemm_grid, 256, 0, stream>>>(agg, x, Wl0, Wr0, b0, g0, be0, out0, n);
    // layer 1
    agg_k<<<agg_grid, 256, 0, stream>>>(out0, offs, csr, agg, n);
    gemm_k<true, true><<<gemm_grid, 256, 0, stream>>>(agg, out0, Wl1, Wr1, b1, g1, be1, out2, n);
    // layer 2 (no bn/relu)
    agg_k<<<agg_grid, 256, 0, stream>>>(out2, offs, csr, agg, n);
    gemm_k<true, false><<<gemm_grid, 256, 0, stream>>>(agg, out2, Wl2, Wr2, b2, nullptr, nullptr, h2, n);
    // heads
    gemm_k<false, false><<<gemm_grid, 256, 0, stream>>>(nullptr, h2, nullptr, dW1, db1, nullptr, nullptr, out0, n);
    gemm_k<false, false><<<gemm_grid, 256, 0, stream>>>(nullptr, h2, nullptr, dW3, db3, nullptr, nullptr, out2, n);
    head2_k<<<nbN, 256, 0, stream>>>(h2, dW2, db2, out1, n);
}

// Round 2
// 463.301 us; speedup vs baseline: 1.6009x; 1.6009x over previous
//
#include <hip/hip_runtime.h>
#include <hip/hip_fp16.h>

static constexpr float kBnEps = 1e-5f;

typedef __attribute__((ext_vector_type(8))) _Float16 f16x8;
typedef __attribute__((ext_vector_type(4))) float f32x4;

// ---------------------------------------------------------------------------
// Edge-index format detection (int64 vs int32 storage).
// ---------------------------------------------------------------------------
__global__ void detect_k(const int* __restrict__ eb, int* __restrict__ flag) {
    int l = threadIdx.x;  // 64 threads
    int v = eb[2 * l + 1];
    unsigned long long m = __ballot(v == 0);
    if (l == 0) flag[0] = (m == ~0ull) ? 1 : 0;
}

__device__ __forceinline__ int edge_src(const int* eb, int is64, int E, int e) {
    return is64 ? eb[2 * e] : eb[e];
}
__device__ __forceinline__ int edge_dst(const int* eb, int is64, int E, int e) {
    return is64 ? eb[2 * E + 2 * e] : eb[E + e];
}

// ---------------------------------------------------------------------------
// Degree histogram
// ---------------------------------------------------------------------------
__global__ void count_k(const int* __restrict__ eb, const int* __restrict__ flag,
                        int* __restrict__ cnt, int E) {
    int e = blockIdx.x * blockDim.x + threadIdx.x;
    if (e >= E) return;
    int is64 = flag[0];
    atomicAdd(&cnt[edge_dst(eb, is64, E, e)], 1);
}

// ---------------------------------------------------------------------------
// Exclusive scan (3 kernels)
// ---------------------------------------------------------------------------
__global__ void scan1_k(const int* __restrict__ cnt, int* __restrict__ offs,
                        int* __restrict__ bsum, int n) {
    __shared__ int s[256];
    int tid = threadIdx.x;
    int i = blockIdx.x * 256 + tid;
    int v = (i < n) ? cnt[i] : 0;
    s[tid] = v;
    __syncthreads();
    for (int d = 1; d < 256; d <<= 1) {
        int t = (tid >= d) ? s[tid - d] : 0;
        __syncthreads();
        s[tid] += t;
        __syncthreads();
    }
    if (i < n) offs[i] = s[tid] - v;
    if (tid == 255) bsum[blockIdx.x] = s[255];
}

__global__ void scan2_k(int* __restrict__ bsum, int nb) {
    __shared__ int s[256];
    int tid = threadIdx.x;
    int v = (tid < nb) ? bsum[tid] : 0;
    s[tid] = v;
    __syncthreads();
    for (int d = 1; d < 256; d <<= 1) {
        int t = (tid >= d) ? s[tid - d] : 0;
        __syncthreads();
        s[tid] += t;
        __syncthreads();
    }
    if (tid < nb) bsum[tid] = s[tid] - v;
}

__global__ void scan3_k(int* __restrict__ offs, const int* __restrict__ bsum,
                        int* __restrict__ cursor, int n, int E) {
    int i = blockIdx.x * 256 + threadIdx.x;
    if (i < n) {
        int o = offs[i] + bsum[i >> 8];
        offs[i] = o;
        cursor[i] = o;
    }
    if (i == 0) offs[n] = E;
}

// ---------------------------------------------------------------------------
// CSR fill
// ---------------------------------------------------------------------------
__global__ void fill_k(const int* __restrict__ eb, const int* __restrict__ flag,
                       int* __restrict__ cursor, int* __restrict__ csr, int E) {
    int e = blockIdx.x * blockDim.x + threadIdx.x;
    if (e >= E) return;
    int is64 = flag[0];
    int s = edge_src(eb, is64, E, e);
    int d = edge_dst(eb, is64, E, e);
    int pos = atomicAdd(&cursor[d], 1);
    csr[pos] = s;
}

// ---------------------------------------------------------------------------
// fp32 -> fp16 feature convert (8 elems/thread)
// ---------------------------------------------------------------------------
__global__ void cvtx_k(const float* __restrict__ in, __half* __restrict__ out, int total8) {
    int i = blockIdx.x * blockDim.x + threadIdx.x;
    if (i >= total8) return;
    float4 v0 = ((const float4*)in)[2 * i];
    float4 v1 = ((const float4*)in)[2 * i + 1];
    __half2 h0 = __floats2half2_rn(v0.x, v0.y);
    __half2 h1 = __floats2half2_rn(v0.z, v0.w);
    __half2 h2 = __floats2half2_rn(v1.x, v1.y);
    __half2 h3 = __floats2half2_rn(v1.z, v1.w);
    uint4 o;
    o.x = *(uint*)&h0; o.y = *(uint*)&h1; o.z = *(uint*)&h2; o.w = *(uint*)&h3;
    ((uint4*)out)[i] = o;
}

// ---------------------------------------------------------------------------
// Weight convert: Wcat[l][n][k] fp16 ([Wl | Wr], K=256) for 3 layers,
// plus dW1h, dW3h [128][128] fp16.
// ---------------------------------------------------------------------------
__global__ void cvtw_k(const float* __restrict__ Wl0, const float* __restrict__ Wr0,
                       const float* __restrict__ Wl1, const float* __restrict__ Wr1,
                       const float* __restrict__ Wl2, const float* __restrict__ Wr2,
                       const float* __restrict__ dW1, const float* __restrict__ dW3,
                       __half* __restrict__ Wcat, __half* __restrict__ dW1h,
                       __half* __restrict__ dW3h) {
    int idx = blockIdx.x * 256 + threadIdx.x;
    if (idx < 3 * 32768) {
        int l = idx >> 15;
        int rem = idx & 32767;
        int nn = rem >> 8;
        int k = rem & 255;
        const float* Wl = (l == 0) ? Wl0 : (l == 1) ? Wl1 : Wl2;
        const float* Wr = (l == 0) ? Wr0 : (l == 1) ? Wr1 : Wr2;
        float v = (k < 128) ? Wl[nn * 128 + k] : Wr[nn * 128 + (k - 128)];
        Wcat[idx] = __float2half_rn(v);
    } else if (idx < 3 * 32768 + 16384) {
        int j = idx - 3 * 32768;
        dW1h[j] = __float2half_rn(dW1[j]);
    } else if (idx < 3 * 32768 + 32768) {
        int j = idx - 3 * 32768 - 16384;
        dW3h[j] = __float2half_rn(dW3[j]);
    }
}

// ---------------------------------------------------------------------------
// Mean aggregation over fp16 rows: one wave per node, lane covers cols
// 2*lane, 2*lane+1 (one dword per row). fp32 accumulate, fp16 store.
// ---------------------------------------------------------------------------
__global__ void agg_k(const __half* __restrict__ Xh, const int* __restrict__ offs,
                      const int* __restrict__ csr, __half* __restrict__ aggh, int n) {
    int gt = blockIdx.x * blockDim.x + threadIdx.x;
    int wid = gt >> 6;
    int lane = threadIdx.x & 63;
    if (wid >= n) return;
    int beg = offs[wid], end = offs[wid + 1];
    float a0 = 0.f, a1 = 0.f;
    for (int j = beg; j < end; ++j) {
        int s = csr[j];  // wave-uniform
        uint v = ((const uint*)Xh)[(size_t)s * 64 + lane];
        __half2 h = *(__half2*)&v;
        a0 += __low2float(h);
        a1 += __high2float(h);
    }
    float inv = 1.0f / fmaxf((float)(end - beg), 1.0f);
    __half2 o = __floats2half2_rn(a0 * inv, a1 * inv);
    ((uint*)aggh)[(size_t)wid * 64 + lane] = *(uint*)&o;
}

// ---------------------------------------------------------------------------
// MFMA GEMM: out = epi( [A0 | A1] @ Bw.T )  (KTOT=256, TWO_SRC)
//        or  out = epi( A0 @ Bw.T )         (KTOT=128, heads)
// Bw is fp16 [128][KTOT] row-major (= W layout, since out = A @ W.T).
// Block: 256 threads = 4 waves; tile 128 rows x 128 cols; whole K in LDS.
// Wave (wm=wid&1, wn=wid>>1) owns rows wm*64..+63, cols wn*64..+63.
// Fragment layout (verified m89): A[m=lane&15][k=(lane>>4)*8+j],
// B[k=(lane>>4)*8+j][n=lane&15]=W[n][k], D[m=(lane>>4)*4+r][n=lane&15].
// Both frags are direct 16B row-major loads -> no transposes.
// ---------------------------------------------------------------------------
template <int KTOT, bool TWO_SRC, bool BN_RELU, bool OUT16>
__global__ __launch_bounds__(256) void mgemm_k(
    const __half* __restrict__ A0, const __half* __restrict__ A1,
    const __half* __restrict__ Bw, const float* __restrict__ bias,
    const float* __restrict__ g, const float* __restrict__ be,
    void* __restrict__ outv, int n) {
    constexpr int ROWB = KTOT * 2 + 16;  // padded row bytes (528 or 272): 2-way banks = free
    __shared__ char sA[128 * ROWB];

    const int tid = threadIdx.x;
    const int lane = tid & 63;
    const int wid = tid >> 6;
    const int wm = wid & 1;
    const int wn = wid >> 1;
    const int row0 = blockIdx.x * 128;

    // ---- stage A rows (fp16) into LDS
    constexpr int CPR = KTOT / 8;  // 16B chunks per row (32 or 16)
#pragma unroll
    for (int i = 0; i < (128 * CPR) / 256; ++i) {
        int idx = tid + i * 256;
        int r = idx / CPR;
        int c = idx % CPR;
        int rg = row0 + r;
        float4 v = make_float4(0.f, 0.f, 0.f, 0.f);
        if (rg < n) {
            if (TWO_SRC)
                v = (c < 16) ? *(const float4*)(A0 + (size_t)rg * 128 + c * 8)
                             : *(const float4*)(A1 + (size_t)rg * 128 + (c - 16) * 8);
            else
                v = *(const float4*)(A0 + (size_t)rg * 128 + c * 8);
        }
        *(float4*)(&sA[r * ROWB + c * 16]) = v;
    }

    f32x4 acc[4][4];
#pragma unroll
    for (int mi = 0; mi < 4; ++mi)
#pragma unroll
        for (int ni = 0; ni < 4; ++ni) acc[mi][ni] = (f32x4){0.f, 0.f, 0.f, 0.f};

    __syncthreads();

    const int bcol = wn * 64;
    constexpr int KH = KTOT / 128;  // 2 or 1
#pragma unroll
    for (int kh = 0; kh < KH; ++kh) {
        // B fragments from global (64KB weight copy, L2/L1-hot)
        f16x8 bfr[4][4];
#pragma unroll
        for (int ni = 0; ni < 4; ++ni)
#pragma unroll
            for (int kt = 0; kt < 4; ++kt) {
                int col = bcol + ni * 16 + (lane & 15);
                int ko = kh * 128 + kt * 32 + (lane >> 4) * 8;
                bfr[ni][kt] = *(const f16x8*)(Bw + (size_t)col * KTOT + ko);
            }
#pragma unroll
        for (int mi = 0; mi < 4; ++mi) {
            int rl = wm * 64 + mi * 16 + (lane & 15);
            const char* base = &sA[rl * ROWB + kh * 256 + (lane >> 4) * 16];
            f16x8 afr[4];
#pragma unroll
            for (int kt = 0; kt < 4; ++kt) afr[kt] = *(const f16x8*)(base + kt * 64);
#pragma unroll
            for (int kt = 0; kt < 4; ++kt)
#pragma unroll
                for (int ni = 0; ni < 4; ++ni)
                    acc[mi][ni] = __builtin_amdgcn_mfma_f32_16x16x32_f16(
                        afr[kt], bfr[ni][kt], acc[mi][ni], 0, 0, 0);
        }
    }

    // ---- epilogue
#pragma unroll
    for (int ni = 0; ni < 4; ++ni) {
        int col = bcol + ni * 16 + (lane & 15);
        float bv = bias[col];
        float gs = 0.f, bes = 0.f;
        if (BN_RELU) {
            gs = g[col] / sqrtf(1.0f + kBnEps);
            bes = be[col];
        }
#pragma unroll
        for (int mi = 0; mi < 4; ++mi) {
#pragma unroll
            for (int r = 0; r < 4; ++r) {
                int row = row0 + wm * 64 + mi * 16 + (lane >> 4) * 4 + r;
                if (row < n) {
                    float v = acc[mi][ni][r] + bv;
                    if (BN_RELU) v = fmaxf(v * gs + bes, 0.f);
                    if (OUT16)
                        ((__half*)outv)[(size_t)row * 128 + col] = __float2half_rn(v);
                    else
                        ((float*)outv)[(size_t)row * 128 + col] = v;
                }
            }
        }
    }
}

// ---------------------------------------------------------------------------
// Tiny head: out[N,7] = h2 @ dW2.T + db2 (h2 fp16, weights fp32 in LDS)
// ---------------------------------------------------------------------------
__global__ __launch_bounds__(256) void head2_k(const __half* __restrict__ h,
                                               const float* __restrict__ W2,
                                               const float* __restrict__ b2,
                                               float* __restrict__ out, int n) {
    __shared__ float sw[7 * 128];
    __shared__ float sb[7];
    int tid = threadIdx.x;
    for (int i = tid; i < 7 * 128; i += 256) sw[i] = W2[i];
    if (tid < 7) sb[tid] = b2[tid];
    __syncthreads();
    int row = blockIdx.x * 256 + tid;
    if (row >= n) return;
    const uint4* hr = (const uint4*)(h + (size_t)row * 128);
    float acc[7] = {0.f, 0.f, 0.f, 0.f, 0.f, 0.f, 0.f};
    for (int q = 0; q < 16; ++q) {  // 16 x 8 halves
        uint4 u = hr[q];
        const __half2* p = (const __half2*)&u;
        float f[8];
#pragma unroll
        for (int t = 0; t < 4; ++t) {
            f[2 * t] = __low2float(p[t]);
            f[2 * t + 1] = __high2float(p[t]);
        }
#pragma unroll
        for (int c = 0; c < 7; ++c)
#pragma unroll
            for (int j = 0; j < 8; ++j) acc[c] += f[j] * sw[c * 128 + q * 8 + j];
    }
#pragma unroll
    for (int c = 0; c < 7; ++c) out[(size_t)row * 7 + c] = acc[c] + sb[c];
}

// ---------------------------------------------------------------------------
extern "C" void kernel_launch(void* const* d_in, const int* in_sizes, int n_in,
                              void* d_out, int out_size, void* d_ws, size_t ws_size,
                              hipStream_t stream) {
    const float* x   = (const float*)d_in[0];
    const int*   eb  = (const int*)d_in[1];
    const float* Wl0 = (const float*)d_in[2];
    const float* Wr0 = (const float*)d_in[3];
    const float* b0  = (const float*)d_in[4];
    const float* Wl1 = (const float*)d_in[5];
    const float* Wr1 = (const float*)d_in[6];
    const float* b1  = (const float*)d_in[7];
    const float* Wl2 = (const float*)d_in[8];
    const float* Wr2 = (const float*)d_in[9];
    const float* b2  = (const float*)d_in[10];
    const float* g0  = (const float*)d_in[11];
    const float* be0 = (const float*)d_in[12];
    const float* g1  = (const float*)d_in[13];
    const float* be1 = (const float*)d_in[14];
    const float* dW1 = (const float*)d_in[15];
    const float* db1 = (const float*)d_in[16];
    const float* dW2 = (const float*)d_in[17];
    const float* db2 = (const float*)d_in[18];
    const float* dW3 = (const float*)d_in[19];
    const float* db3 = (const float*)d_in[20];

    const int n = in_sizes[0] / 128;
    const int E = in_sizes[1] / 2;

    char* ws = (char*)d_ws;
    size_t off = 0;
    auto alloc = [&](size_t bytes) -> void* {
        void* p = ws + off;
        off = (off + bytes + 255) & ~(size_t)255;
        return p;
    };
    int*    flag   = (int*)alloc(16);
    int*    cnt    = (int*)alloc((size_t)n * 4);
    int*    offs   = (int*)alloc((size_t)(n + 1) * 4);
    int*    bsum   = (int*)alloc(1024);
    int*    cursor = (int*)alloc((size_t)n * 4);
    int*    csr    = (int*)alloc((size_t)E * 4);
    __half* x_h    = (__half*)alloc((size_t)n * 128 * 2);
    __half* agg_h  = (__half*)alloc((size_t)n * 128 * 2);
    __half* h0     = (__half*)alloc((size_t)n * 128 * 2);
    __half* h1     = (__half*)alloc((size_t)n * 128 * 2);
    __half* h2     = h0;  // h0 dead after layer-1 gemm
    __half* Wcat   = (__half*)alloc(3 * 32768 * 2);
    __half* dW1h   = (__half*)alloc(16384 * 2);
    __half* dW3h   = (__half*)alloc(16384 * 2);

    float* out0 = (float*)d_out;
    float* out1 = out0 + (size_t)n * 128;
    float* out2 = out1 + (size_t)n * 7;

    hipMemsetAsync(cnt, 0, (size_t)n * 4, stream);

    const int nbN = (n + 255) / 256;
    const int nbE = (E + 255) / 256;
    const int ggrid = (n + 127) / 128;
    const int agg_grid = (n * 64 + 255) / 256;

    detect_k<<<1, 64, 0, stream>>>(eb, flag);
    count_k<<<nbE, 256, 0, stream>>>(eb, flag, cnt, E);
    scan1_k<<<nbN, 256, 0, stream>>>(cnt, offs, bsum, n);
    scan2_k<<<1, 256, 0, stream>>>(bsum, nbN);
    scan3_k<<<nbN, 256, 0, stream>>>(offs, bsum, cursor, n, E);
    fill_k<<<nbE, 256, 0, stream>>>(eb, flag, cursor, csr, E);

    cvtx_k<<<(n * 16 + 255) / 256, 256, 0, stream>>>(x, x_h, n * 16);
    cvtw_k<<<(131072 + 255) / 256, 256, 0, stream>>>(Wl0, Wr0, Wl1, Wr1, Wl2, Wr2,
                                                     dW1, dW3, Wcat, dW1h, dW3h);

    // layer 0
    agg_k<<<agg_grid, 256, 0, stream>>>(x_h, offs, csr, agg_h, n);
    mgemm_k<256, true, true, true><<<ggrid, 256, 0, stream>>>(
        agg_h, x_h, Wcat, b0, g0, be0, h0, n);
    // layer 1
    agg_k<<<agg_grid, 256, 0, stream>>>(h0, offs, csr, agg_h, n);
    mgemm_k<256, true, true, true><<<ggrid, 256, 0, stream>>>(
        agg_h, h0, Wcat + 32768, b1, g1, be1, h1, n);
    // layer 2 (no bn/relu); h2 aliases h0 (h0 dead now)
    agg_k<<<agg_grid, 256, 0, stream>>>(h1, offs, csr, agg_h, n);
    mgemm_k<256, true, false, true><<<ggrid, 256, 0, stream>>>(
        agg_h, h1, Wcat + 65536, b2, nullptr, nullptr, h2, n);
    // heads
    mgemm_k<128, false, false, false><<<ggrid, 256, 0, stream>>>(
        h2, nullptr, dW1h, db1, nullptr, nullptr, out0, n);
    mgemm_k<128, false, false, false><<<ggrid, 256, 0, stream>>>(
        h2, nullptr, dW3h, db3, nullptr, nullptr, out2, n);
    head2_k<<<nbN, 256, 0, stream>>>(h2, dW2, db2, out1, n);
}

// Round 3
// 321.968 us; speedup vs baseline: 2.3036x; 1.4390x over previous
//
#include <hip/hip_runtime.h>
#include <hip/hip_fp16.h>

static constexpr float kBnEps = 1e-5f;

typedef __attribute__((ext_vector_type(8))) _Float16 f16x8;
typedef __attribute__((ext_vector_type(4))) float f32x4;

// ---------------------------------------------------------------------------
// Edge-index format detection (int64 vs int32 storage).
// ---------------------------------------------------------------------------
__global__ void detect_k(const int* __restrict__ eb, int* __restrict__ flag) {
    int l = threadIdx.x;  // 64 threads
    int v = eb[2 * l + 1];
    unsigned long long m = __ballot(v == 0);
    if (l == 0) flag[0] = (m == ~0ull) ? 1 : 0;
}

__device__ __forceinline__ int edge_src(const int* eb, int is64, int E, int e) {
    return is64 ? eb[2 * e] : eb[e];
}
__device__ __forceinline__ int edge_dst(const int* eb, int is64, int E, int e) {
    return is64 ? eb[2 * E + 2 * e] : eb[E + e];
}

// ---------------------------------------------------------------------------
// Degree histogram
// ---------------------------------------------------------------------------
__global__ void count_k(const int* __restrict__ eb, const int* __restrict__ flag,
                        int* __restrict__ cnt, int E) {
    int e = blockIdx.x * blockDim.x + threadIdx.x;
    if (e >= E) return;
    int is64 = flag[0];
    atomicAdd(&cnt[edge_dst(eb, is64, E, e)], 1);
}

// ---------------------------------------------------------------------------
// Exclusive scan (3 kernels)
// ---------------------------------------------------------------------------
__global__ void scan1_k(const int* __restrict__ cnt, int* __restrict__ offs,
                        int* __restrict__ bsum, int n) {
    __shared__ int s[256];
    int tid = threadIdx.x;
    int i = blockIdx.x * 256 + tid;
    int v = (i < n) ? cnt[i] : 0;
    s[tid] = v;
    __syncthreads();
    for (int d = 1; d < 256; d <<= 1) {
        int t = (tid >= d) ? s[tid - d] : 0;
        __syncthreads();
        s[tid] += t;
        __syncthreads();
    }
    if (i < n) offs[i] = s[tid] - v;
    if (tid == 255) bsum[blockIdx.x] = s[255];
}

__global__ void scan2_k(int* __restrict__ bsum, int nb) {
    __shared__ int s[256];
    int tid = threadIdx.x;
    int v = (tid < nb) ? bsum[tid] : 0;
    s[tid] = v;
    __syncthreads();
    for (int d = 1; d < 256; d <<= 1) {
        int t = (tid >= d) ? s[tid - d] : 0;
        __syncthreads();
        s[tid] += t;
        __syncthreads();
    }
    if (tid < nb) bsum[tid] = s[tid] - v;
}

__global__ void scan3_k(int* __restrict__ offs, const int* __restrict__ bsum,
                        int* __restrict__ cursor, int n, int E) {
    int i = blockIdx.x * 256 + threadIdx.x;
    if (i < n) {
        int o = offs[i] + bsum[i >> 8];
        offs[i] = o;
        cursor[i] = o;
    }
    if (i == 0) offs[n] = E;
}

// ---------------------------------------------------------------------------
// CSR fill
// ---------------------------------------------------------------------------
__global__ void fill_k(const int* __restrict__ eb, const int* __restrict__ flag,
                       int* __restrict__ cursor, int* __restrict__ csr, int E) {
    int e = blockIdx.x * blockDim.x + threadIdx.x;
    if (e >= E) return;
    int is64 = flag[0];
    int s = edge_src(eb, is64, E, e);
    int d = edge_dst(eb, is64, E, e);
    int pos = atomicAdd(&cursor[d], 1);
    csr[pos] = s;
}

// ---------------------------------------------------------------------------
// fp32 -> fp16 feature convert (8 elems/thread)
// ---------------------------------------------------------------------------
__global__ void cvtx_k(const float* __restrict__ in, __half* __restrict__ out, int total8) {
    int i = blockIdx.x * blockDim.x + threadIdx.x;
    if (i >= total8) return;
    float4 v0 = ((const float4*)in)[2 * i];
    float4 v1 = ((const float4*)in)[2 * i + 1];
    __half2 h0 = __floats2half2_rn(v0.x, v0.y);
    __half2 h1 = __floats2half2_rn(v0.z, v0.w);
    __half2 h2 = __floats2half2_rn(v1.x, v1.y);
    __half2 h3 = __floats2half2_rn(v1.z, v1.w);
    uint4 o;
    o.x = *(uint*)&h0; o.y = *(uint*)&h1; o.z = *(uint*)&h2; o.w = *(uint*)&h3;
    ((uint4*)out)[i] = o;
}

// ---------------------------------------------------------------------------
// Weight convert: Wcat[l][n][k] fp16 ([Wl | Wr], K=256) for 3 layers,
// plus dWcat [256][128] fp16 (rows 0..127 = dW1, rows 128..255 = dW3).
// ---------------------------------------------------------------------------
__global__ void cvtw_k(const float* __restrict__ Wl0, const float* __restrict__ Wr0,
                       const float* __restrict__ Wl1, const float* __restrict__ Wr1,
                       const float* __restrict__ Wl2, const float* __restrict__ Wr2,
                       const float* __restrict__ dW1, const float* __restrict__ dW3,
                       __half* __restrict__ Wcat, __half* __restrict__ dWcat) {
    int idx = blockIdx.x * 256 + threadIdx.x;
    if (idx < 3 * 32768) {
        int l = idx >> 15;
        int rem = idx & 32767;
        int nn = rem >> 8;
        int k = rem & 255;
        const float* Wl = (l == 0) ? Wl0 : (l == 1) ? Wl1 : Wl2;
        const float* Wr = (l == 0) ? Wr0 : (l == 1) ? Wr1 : Wr2;
        float v = (k < 128) ? Wl[nn * 128 + k] : Wr[nn * 128 + (k - 128)];
        Wcat[idx] = __float2half_rn(v);
    } else if (idx < 3 * 32768 + 16384) {
        int j = idx - 3 * 32768;
        dWcat[j] = __float2half_rn(dW1[j]);
    } else if (idx < 3 * 32768 + 32768) {
        int j = idx - 3 * 32768 - 16384;
        dWcat[16384 + j] = __float2half_rn(dW3[j]);
    }
}

// ---------------------------------------------------------------------------
// Mean aggregation over fp16 rows: one wave per node, lane covers cols
// 2*lane, 2*lane+1 (one dword per row). 8-deep predicated batching for MLP:
// 8 independent index loads, then 8 independent 256B row loads in flight.
// fp32 accumulate, fp16 store.
// ---------------------------------------------------------------------------
__global__ void agg_k(const __half* __restrict__ Xh, const int* __restrict__ offs,
                      const int* __restrict__ csr, __half* __restrict__ aggh, int n) {
    int gt = blockIdx.x * blockDim.x + threadIdx.x;
    int wid = gt >> 6;
    int lane = threadIdx.x & 63;
    if (wid >= n) return;
    int beg = offs[wid], end = offs[wid + 1];
    int len = end - beg;
    const uint* Xp = (const uint*)Xh;
    float a0 = 0.f, a1 = 0.f;
    for (int j0 = 0; j0 < len; j0 += 8) {
        int idx[8];
        float w[8];
#pragma unroll
        for (int t = 0; t < 8; ++t) {
            int jj = j0 + t;
            bool ok = jj < len;
            idx[t] = csr[beg + (ok ? jj : 0)];  // 8 independent loads
            w[t] = ok ? 1.f : 0.f;
        }
        uint v[8];
#pragma unroll
        for (int t = 0; t < 8; ++t)
            v[t] = Xp[(size_t)idx[t] * 64 + lane];  // 8 independent row loads
#pragma unroll
        for (int t = 0; t < 8; ++t) {
            __half2 h = *(__half2*)&v[t];
            a0 += w[t] * __low2float(h);
            a1 += w[t] * __high2float(h);
        }
    }
    float inv = 1.0f / fmaxf((float)len, 1.0f);
    __half2 o = __floats2half2_rn(a0 * inv, a1 * inv);
    ((uint*)aggh)[(size_t)wid * 64 + lane] = *(uint*)&o;
}

// ---------------------------------------------------------------------------
// MFMA GEMM: out = epi( [A0 | A1] @ Bw.T )  (KTOT=256, TWO_SRC)
//        or  out = epi( A0 @ Bw.T )         (KTOT=128, heads)
// Bw is fp16 [128][KTOT] row-major (= W layout, since out = A @ W.T).
// Block: 256 threads = 4 waves; tile 128 rows x 128 cols; whole K in LDS.
// gridDim.y==2 selects second 128-row weight block + second output (heads).
// ---------------------------------------------------------------------------
template <int KTOT, bool TWO_SRC, bool BN_RELU, bool OUT16>
__global__ __launch_bounds__(256) void mgemm_k(
    const __half* __restrict__ A0, const __half* __restrict__ A1,
    const __half* __restrict__ Bw, const float* __restrict__ bias,
    const float* __restrict__ g, const float* __restrict__ be,
    void* __restrict__ outv, const float* __restrict__ bias2,
    void* __restrict__ outv2, int n) {
    constexpr int ROWB = KTOT * 2 + 16;  // padded row bytes: 2-way banks = free
    __shared__ char sA[128 * ROWB];

    if (blockIdx.y == 1) {  // second head: dW3 block + out2
        Bw += 128 * KTOT;
        bias = bias2;
        outv = outv2;
    }

    const int tid = threadIdx.x;
    const int lane = tid & 63;
    const int wid = tid >> 6;
    const int wm = wid & 1;
    const int wn = wid >> 1;
    const int row0 = blockIdx.x * 128;

    // ---- stage A rows (fp16) into LDS
    constexpr int CPR = KTOT / 8;  // 16B chunks per row (32 or 16)
#pragma unroll
    for (int i = 0; i < (128 * CPR) / 256; ++i) {
        int idx = tid + i * 256;
        int r = idx / CPR;
        int c = idx % CPR;
        int rg = row0 + r;
        float4 v = make_float4(0.f, 0.f, 0.f, 0.f);
        if (rg < n) {
            if (TWO_SRC)
                v = (c < 16) ? *(const float4*)(A0 + (size_t)rg * 128 + c * 8)
                             : *(const float4*)(A1 + (size_t)rg * 128 + (c - 16) * 8);
            else
                v = *(const float4*)(A0 + (size_t)rg * 128 + c * 8);
        }
        *(float4*)(&sA[r * ROWB + c * 16]) = v;
    }

    f32x4 acc[4][4];
#pragma unroll
    for (int mi = 0; mi < 4; ++mi)
#pragma unroll
        for (int ni = 0; ni < 4; ++ni) acc[mi][ni] = (f32x4){0.f, 0.f, 0.f, 0.f};

    __syncthreads();

    const int bcol = wn * 64;
    constexpr int KH = KTOT / 128;  // 2 or 1
#pragma unroll
    for (int kh = 0; kh < KH; ++kh) {
        f16x8 bfr[4][4];
#pragma unroll
        for (int ni = 0; ni < 4; ++ni)
#pragma unroll
            for (int kt = 0; kt < 4; ++kt) {
                int col = bcol + ni * 16 + (lane & 15);
                int ko = kh * 128 + kt * 32 + (lane >> 4) * 8;
                bfr[ni][kt] = *(const f16x8*)(Bw + (size_t)col * KTOT + ko);
            }
#pragma unroll
        for (int mi = 0; mi < 4; ++mi) {
            int rl = wm * 64 + mi * 16 + (lane & 15);
            const char* base = &sA[rl * ROWB + kh * 256 + (lane >> 4) * 16];
            f16x8 afr[4];
#pragma unroll
            for (int kt = 0; kt < 4; ++kt) afr[kt] = *(const f16x8*)(base + kt * 64);
#pragma unroll
            for (int kt = 0; kt < 4; ++kt)
#pragma unroll
                for (int ni = 0; ni < 4; ++ni)
                    acc[mi][ni] = __builtin_amdgcn_mfma_f32_16x16x32_f16(
                        afr[kt], bfr[ni][kt], acc[mi][ni], 0, 0, 0);
        }
    }

    // ---- epilogue
#pragma unroll
    for (int ni = 0; ni < 4; ++ni) {
        int col = bcol + ni * 16 + (lane & 15);
        float bv = bias[col];
        float gs = 0.f, bes = 0.f;
        if (BN_RELU) {
            gs = g[col] / sqrtf(1.0f + kBnEps);
            bes = be[col];
        }
#pragma unroll
        for (int mi = 0; mi < 4; ++mi) {
#pragma unroll
            for (int r = 0; r < 4; ++r) {
                int row = row0 + wm * 64 + mi * 16 + (lane >> 4) * 4 + r;
                if (row < n) {
                    float v = acc[mi][ni][r] + bv;
                    if (BN_RELU) v = fmaxf(v * gs + bes, 0.f);
                    if (OUT16)
                        ((__half*)outv)[(size_t)row * 128 + col] = __float2half_rn(v);
                    else
                        ((float*)outv)[(size_t)row * 128 + col] = v;
                }
            }
        }
    }
}

// ---------------------------------------------------------------------------
// Tiny head: out[N,7] = h2 @ dW2.T + db2 (h2 fp16, weights fp32 in LDS)
// ---------------------------------------------------------------------------
__global__ __launch_bounds__(256) void head2_k(const __half* __restrict__ h,
                                               const float* __restrict__ W2,
                                               const float* __restrict__ b2,
                                               float* __restrict__ out, int n) {
    __shared__ float sw[7 * 128];
    __shared__ float sb[7];
    int tid = threadIdx.x;
    for (int i = tid; i < 7 * 128; i += 256) sw[i] = W2[i];
    if (tid < 7) sb[tid] = b2[tid];
    __syncthreads();
    int row = blockIdx.x * 256 + tid;
    if (row >= n) return;
    const uint4* hr = (const uint4*)(h + (size_t)row * 128);
    float acc[7] = {0.f, 0.f, 0.f, 0.f, 0.f, 0.f, 0.f};
    for (int q = 0; q < 16; ++q) {
        uint4 u = hr[q];
        const __half2* p = (const __half2*)&u;
        float f[8];
#pragma unroll
        for (int t = 0; t < 4; ++t) {
            f[2 * t] = __low2float(p[t]);
            f[2 * t + 1] = __high2float(p[t]);
        }
#pragma unroll
        for (int c = 0; c < 7; ++c)
#pragma unroll
            for (int j = 0; j < 8; ++j) acc[c] += f[j] * sw[c * 128 + q * 8 + j];
    }
#pragma unroll
    for (int c = 0; c < 7; ++c) out[(size_t)row * 7 + c] = acc[c] + sb[c];
}

// ---------------------------------------------------------------------------
extern "C" void kernel_launch(void* const* d_in, const int* in_sizes, int n_in,
                              void* d_out, int out_size, void* d_ws, size_t ws_size,
                              hipStream_t stream) {
    const float* x   = (const float*)d_in[0];
    const int*   eb  = (const int*)d_in[1];
    const float* Wl0 = (const float*)d_in[2];
    const float* Wr0 = (const float*)d_in[3];
    const float* b0  = (const float*)d_in[4];
    const float* Wl1 = (const float*)d_in[5];
    const float* Wr1 = (const float*)d_in[6];
    const float* b1  = (const float*)d_in[7];
    const float* Wl2 = (const float*)d_in[8];
    const float* Wr2 = (const float*)d_in[9];
    const float* b2  = (const float*)d_in[10];
    const float* g0  = (const float*)d_in[11];
    const float* be0 = (const float*)d_in[12];
    const float* g1  = (const float*)d_in[13];
    const float* be1 = (const float*)d_in[14];
    const float* dW1 = (const float*)d_in[15];
    const float* db1 = (const float*)d_in[16];
    const float* dW2 = (const float*)d_in[17];
    const float* db2 = (const float*)d_in[18];
    const float* dW3 = (const float*)d_in[19];
    const float* db3 = (const float*)d_in[20];

    const int n = in_sizes[0] / 128;
    const int E = in_sizes[1] / 2;

    char* ws = (char*)d_ws;
    size_t off = 0;
    auto alloc = [&](size_t bytes) -> void* {
        void* p = ws + off;
        off = (off + bytes + 255) & ~(size_t)255;
        return p;
    };
    int*    flag   = (int*)alloc(16);
    int*    cnt    = (int*)alloc((size_t)n * 4);
    int*    offs   = (int*)alloc((size_t)(n + 1) * 4);
    int*    bsum   = (int*)alloc(1024);
    int*    cursor = (int*)alloc((size_t)n * 4);
    int*    csr    = (int*)alloc((size_t)E * 4);
    __half* x_h    = (__half*)alloc((size_t)n * 128 * 2);
    __half* agg_h  = (__half*)alloc((size_t)n * 128 * 2);
    __half* h0     = (__half*)alloc((size_t)n * 128 * 2);
    __half* h1     = (__half*)alloc((size_t)n * 128 * 2);
    __half* h2     = h0;  // h0 dead after layer-1 gemm
    __half* Wcat   = (__half*)alloc(3 * 32768 * 2);
    __half* dWcat  = (__half*)alloc(32768 * 2);

    float* out0 = (float*)d_out;
    float* out1 = out0 + (size_t)n * 128;
    float* out2 = out1 + (size_t)n * 7;

    hipMemsetAsync(cnt, 0, (size_t)n * 4, stream);

    const int nbN = (n + 255) / 256;
    const int nbE = (E + 255) / 256;
    const int ggrid = (n + 127) / 128;
    const int agg_grid = (n * 64 + 255) / 256;

    detect_k<<<1, 64, 0, stream>>>(eb, flag);
    count_k<<<nbE, 256, 0, stream>>>(eb, flag, cnt, E);
    scan1_k<<<nbN, 256, 0, stream>>>(cnt, offs, bsum, n);
    scan2_k<<<1, 256, 0, stream>>>(bsum, nbN);
    scan3_k<<<nbN, 256, 0, stream>>>(offs, bsum, cursor, n, E);
    fill_k<<<nbE, 256, 0, stream>>>(eb, flag, cursor, csr, E);

    cvtx_k<<<(n * 16 + 255) / 256, 256, 0, stream>>>(x, x_h, n * 16);
    cvtw_k<<<(131072 + 255) / 256, 256, 0, stream>>>(Wl0, Wr0, Wl1, Wr1, Wl2, Wr2,
                                                     dW1, dW3, Wcat, dWcat);

    // layer 0
    agg_k<<<agg_grid, 256, 0, stream>>>(x_h, offs, csr, agg_h, n);
    mgemm_k<256, true, true, true><<<ggrid, 256, 0, stream>>>(
        agg_h, x_h, Wcat, b0, g0, be0, h0, nullptr, nullptr, n);
    // layer 1
    agg_k<<<agg_grid, 256, 0, stream>>>(h0, offs, csr, agg_h, n);
    mgemm_k<256, true, true, true><<<ggrid, 256, 0, stream>>>(
        agg_h, h0, Wcat + 32768, b1, g1, be1, h1, nullptr, nullptr, n);
    // layer 2 (no bn/relu); h2 aliases h0
    agg_k<<<agg_grid, 256, 0, stream>>>(h1, offs, csr, agg_h, n);
    mgemm_k<256, true, false, true><<<ggrid, 256, 0, stream>>>(
        agg_h, h1, Wcat + 65536, b2, nullptr, nullptr, h2, nullptr, nullptr, n);
    // fused heads: blockIdx.y==0 -> dW1/db1 -> out0; ==1 -> dW3/db3 -> out2
    mgemm_k<128, false, false, false><<<dim3(ggrid, 2), 256, 0, stream>>>(
        h2, nullptr, dWcat, db1, nullptr, nullptr, out0, db3, out2, n);
    head2_k<<<nbN, 256, 0, stream>>>(h2, dW2, db2, out1, n);
}

// Round 4
// 253.875 us; speedup vs baseline: 2.9215x; 1.2682x over previous
//
#include <hip/hip_runtime.h>
#include <hip/hip_fp16.h>

static constexpr float kBnEps = 1e-5f;
static constexpr int MAXB = 1024;  // max dst-buckets (128 dsts each)

typedef __attribute__((ext_vector_type(8))) _Float16 f16x8;
typedef __attribute__((ext_vector_type(4))) float f32x4;

// ---------------------------------------------------------------------------
// Edge-index format detection (int64 vs int32 storage).
// ---------------------------------------------------------------------------
__global__ void detect_k(const int* __restrict__ eb, int* __restrict__ flag) {
    int l = threadIdx.x;  // 64 threads
    int v = eb[2 * l + 1];
    unsigned long long m = __ballot(v == 0);
    if (l == 0) flag[0] = (m == ~0ull) ? 1 : 0;
}

__device__ __forceinline__ int edge_src(const int* eb, int is64, int E, int e) {
    return is64 ? eb[2 * e] : eb[e];
}
__device__ __forceinline__ int edge_dst(const int* eb, int is64, int E, int e) {
    return is64 ? eb[2 * E + 2 * e] : eb[E + e];
}

// ---------------------------------------------------------------------------
// CSR build, bucket-sort version. Buckets = dst>>7 (128 dsts each).
// ---------------------------------------------------------------------------
// Pass A: per-WG LDS histogram of bucket sizes, flushed with few global atomics
__global__ __launch_bounds__(256) void histA_k(const int* __restrict__ eb,
                                               const int* __restrict__ flag,
                                               int* __restrict__ gcnt, int E,
                                               int nbuck) {
    __shared__ int lh[MAXB];
    for (int i = threadIdx.x; i < nbuck; i += 256) lh[i] = 0;
    __syncthreads();
    int is64 = flag[0];
    int base = blockIdx.x * 4096;
#pragma unroll
    for (int i = 0; i < 16; ++i) {
        int e = base + i * 256 + threadIdx.x;
        if (e < E) {
            int d = edge_dst(eb, is64, E, e);
            atomicAdd(&lh[d >> 7], 1);
        }
    }
    __syncthreads();
    for (int i = threadIdx.x; i < nbuck; i += 256) {
        int c = lh[i];
        if (c) atomicAdd(&gcnt[i], c);
    }
}

// Pass B: single-WG scan of bucket counts -> bases + cursors
__global__ __launch_bounds__(512) void scanB_k(const int* __restrict__ gcnt,
                                               int* __restrict__ gbase,
                                               int* __restrict__ gcur,
                                               int* __restrict__ offs, int E,
                                               int n, int nbuck) {
    __shared__ int s[512];
    int tid = threadIdx.x;
    int v = (tid < nbuck) ? gcnt[tid] : 0;
    s[tid] = v;
    __syncthreads();
    for (int d = 1; d < 512; d <<= 1) {
        int t = (tid >= d) ? s[tid - d] : 0;
        __syncthreads();
        s[tid] += t;
        __syncthreads();
    }
    if (tid < nbuck) {
        gbase[tid] = s[tid] - v;
        gcur[tid] = s[tid] - v;
    }
    if (tid == 0) {
        gbase[nbuck] = E;
        offs[n] = E;
    }
}

// Pass C: bin edges into bucket regions as packed (src<<7 | dst&127).
// Per-WG: LDS count, one global atomic per bucket to reserve a run, scatter.
__global__ __launch_bounds__(256) void binC_k(const int* __restrict__ eb,
                                              const int* __restrict__ flag,
                                              int* __restrict__ gcur,
                                              unsigned* __restrict__ bins, int E,
                                              int nbuck) {
    __shared__ int lh[MAXB];
    __shared__ int lcur[MAXB];
    for (int i = threadIdx.x; i < nbuck; i += 256) lh[i] = 0;
    __syncthreads();
    int is64 = flag[0];
    int base = blockIdx.x * 4096;
    int ds[16], ss[16];
#pragma unroll
    for (int i = 0; i < 16; ++i) {
        int e = base + i * 256 + threadIdx.x;
        ds[i] = -1;
        if (e < E) {
            ds[i] = edge_dst(eb, is64, E, e);
            ss[i] = edge_src(eb, is64, E, e);
            atomicAdd(&lh[ds[i] >> 7], 1);
        }
    }
    __syncthreads();
    for (int b = threadIdx.x; b < nbuck; b += 256) {
        int c = lh[b];
        lcur[b] = c ? atomicAdd(&gcur[b], c) : 0;
    }
    __syncthreads();
#pragma unroll
    for (int i = 0; i < 16; ++i) {
        if (ds[i] >= 0) {
            int bkt = ds[i] >> 7;
            int p = atomicAdd(&lcur[bkt], 1);
            bins[p] = ((unsigned)ss[i] << 7) | (unsigned)(ds[i] & 127);
        }
    }
}

// Pass D: one WG per bucket: 128-slot LDS hist + scan -> offs[] and csr[].
__global__ __launch_bounds__(256) void csrD_k(const unsigned* __restrict__ bins,
                                              const int* __restrict__ gbase,
                                              int* __restrict__ offs,
                                              int* __restrict__ csr, int n) {
    int b = blockIdx.x;
    __shared__ int hist[128];
    __shared__ int s[128];
    __shared__ int cur[128];
    int tid = threadIdx.x;
    if (tid < 128) hist[tid] = 0;
    __syncthreads();
    int base = gbase[b], endb = gbase[b + 1], m = endb - base;
    for (int i = tid; i < m; i += 256) atomicAdd(&hist[bins[base + i] & 127u], 1);
    __syncthreads();
    int v = 0;
    if (tid < 128) {
        v = hist[tid];
        s[tid] = v;
    }
    __syncthreads();
    for (int d = 1; d < 128; d <<= 1) {
        int t = (tid >= d && tid < 128) ? s[tid - d] : 0;
        __syncthreads();
        if (tid < 128) s[tid] += t;
        __syncthreads();
    }
    if (tid < 128) {
        int excl = s[tid] - v;
        int dst = b * 128 + tid;
        if (dst < n) offs[dst] = base + excl;
        cur[tid] = base + excl;
    }
    __syncthreads();
    for (int i = tid; i < m; i += 256) {
        unsigned u = bins[base + i];
        int p = atomicAdd(&cur[u & 127u], 1);
        csr[p] = (int)(u >> 7);
    }
}

// ---------------------------------------------------------------------------
// fp32 -> fp16 feature convert (8 elems/thread)
// ---------------------------------------------------------------------------
__global__ void cvtx_k(const float* __restrict__ in, __half* __restrict__ out, int total8) {
    int i = blockIdx.x * blockDim.x + threadIdx.x;
    if (i >= total8) return;
    float4 v0 = ((const float4*)in)[2 * i];
    float4 v1 = ((const float4*)in)[2 * i + 1];
    __half2 h0 = __floats2half2_rn(v0.x, v0.y);
    __half2 h1 = __floats2half2_rn(v0.z, v0.w);
    __half2 h2 = __floats2half2_rn(v1.x, v1.y);
    __half2 h3 = __floats2half2_rn(v1.z, v1.w);
    uint4 o;
    o.x = *(uint*)&h0; o.y = *(uint*)&h1; o.z = *(uint*)&h2; o.w = *(uint*)&h3;
    ((uint4*)out)[i] = o;
}

// ---------------------------------------------------------------------------
// Weight convert: Wcat[l][n][k] fp16 ([Wl | Wr], K=256) for 3 layers,
// plus dWcat [256][128] fp16 (rows 0..127 = dW1, rows 128..255 = dW3).
// ---------------------------------------------------------------------------
__global__ void cvtw_k(const float* __restrict__ Wl0, const float* __restrict__ Wr0,
                       const float* __restrict__ Wl1, const float* __restrict__ Wr1,
                       const float* __restrict__ Wl2, const float* __restrict__ Wr2,
                       const float* __restrict__ dW1, const float* __restrict__ dW3,
                       __half* __restrict__ Wcat, __half* __restrict__ dWcat) {
    int idx = blockIdx.x * 256 + threadIdx.x;
    if (idx < 3 * 32768) {
        int l = idx >> 15;
        int rem = idx & 32767;
        int nn = rem >> 8;
        int k = rem & 255;
        const float* Wl = (l == 0) ? Wl0 : (l == 1) ? Wl1 : Wl2;
        const float* Wr = (l == 0) ? Wr0 : (l == 1) ? Wr1 : Wr2;
        float v = (k < 128) ? Wl[nn * 128 + k] : Wr[nn * 128 + (k - 128)];
        Wcat[idx] = __float2half_rn(v);
    } else if (idx < 3 * 32768 + 16384) {
        int j = idx - 3 * 32768;
        dWcat[j] = __float2half_rn(dW1[j]);
    } else if (idx < 3 * 32768 + 32768) {
        int j = idx - 3 * 32768 - 16384;
        dWcat[16384 + j] = __float2half_rn(dW3[j]);
    }
}

// ---------------------------------------------------------------------------
// Mean aggregation over fp16 rows: one wave per node, lane covers cols
// 2*lane, 2*lane+1. 8-deep predicated batching for MLP. fp32 accumulate.
// ---------------------------------------------------------------------------
__global__ void agg_k(const __half* __restrict__ Xh, const int* __restrict__ offs,
                      const int* __restrict__ csr, __half* __restrict__ aggh, int n) {
    int gt = blockIdx.x * blockDim.x + threadIdx.x;
    int wid = gt >> 6;
    int lane = threadIdx.x & 63;
    if (wid >= n) return;
    int beg = offs[wid], end = offs[wid + 1];
    int len = end - beg;
    const uint* Xp = (const uint*)Xh;
    float a0 = 0.f, a1 = 0.f;
    for (int j0 = 0; j0 < len; j0 += 8) {
        int idx[8];
        float w[8];
#pragma unroll
        for (int t = 0; t < 8; ++t) {
            int jj = j0 + t;
            bool ok = jj < len;
            idx[t] = csr[beg + (ok ? jj : 0)];
            w[t] = ok ? 1.f : 0.f;
        }
        uint v[8];
#pragma unroll
        for (int t = 0; t < 8; ++t)
            v[t] = Xp[(size_t)idx[t] * 64 + lane];
#pragma unroll
        for (int t = 0; t < 8; ++t) {
            __half2 h = *(__half2*)&v[t];
            a0 += w[t] * __low2float(h);
            a1 += w[t] * __high2float(h);
        }
    }
    float inv = 1.0f / fmaxf((float)len, 1.0f);
    __half2 o = __floats2half2_rn(a0 * inv, a1 * inv);
    ((uint*)aggh)[(size_t)wid * 64 + lane] = *(uint*)&o;
}

// ---------------------------------------------------------------------------
// MFMA GEMM: out = epi( [A0 | A1] @ Bw.T )  (KTOT=256, TWO_SRC)
//        or  out = epi( A0 @ Bw.T )         (KTOT=128, heads)
// gridDim.y==2 selects second 128-row weight block + second output (heads).
// ---------------------------------------------------------------------------
template <int KTOT, bool TWO_SRC, bool BN_RELU, bool OUT16>
__global__ __launch_bounds__(256) void mgemm_k(
    const __half* __restrict__ A0, const __half* __restrict__ A1,
    const __half* __restrict__ Bw, const float* __restrict__ bias,
    const float* __restrict__ g, const float* __restrict__ be,
    void* __restrict__ outv, const float* __restrict__ bias2,
    void* __restrict__ outv2, int n) {
    constexpr int ROWB = KTOT * 2 + 16;  // padded row bytes: 2-way banks = free
    __shared__ char sA[128 * ROWB];

    if (blockIdx.y == 1) {  // second head: dW3 block + out2
        Bw += 128 * KTOT;
        bias = bias2;
        outv = outv2;
    }

    const int tid = threadIdx.x;
    const int lane = tid & 63;
    const int wid = tid >> 6;
    const int wm = wid & 1;
    const int wn = wid >> 1;
    const int row0 = blockIdx.x * 128;

    constexpr int CPR = KTOT / 8;  // 16B chunks per row
#pragma unroll
    for (int i = 0; i < (128 * CPR) / 256; ++i) {
        int idx = tid + i * 256;
        int r = idx / CPR;
        int c = idx % CPR;
        int rg = row0 + r;
        float4 v = make_float4(0.f, 0.f, 0.f, 0.f);
        if (rg < n) {
            if (TWO_SRC)
                v = (c < 16) ? *(const float4*)(A0 + (size_t)rg * 128 + c * 8)
                             : *(const float4*)(A1 + (size_t)rg * 128 + (c - 16) * 8);
            else
                v = *(const float4*)(A0 + (size_t)rg * 128 + c * 8);
        }
        *(float4*)(&sA[r * ROWB + c * 16]) = v;
    }

    f32x4 acc[4][4];
#pragma unroll
    for (int mi = 0; mi < 4; ++mi)
#pragma unroll
        for (int ni = 0; ni < 4; ++ni) acc[mi][ni] = (f32x4){0.f, 0.f, 0.f, 0.f};

    __syncthreads();

    const int bcol = wn * 64;
    constexpr int KH = KTOT / 128;
#pragma unroll
    for (int kh = 0; kh < KH; ++kh) {
        f16x8 bfr[4][4];
#pragma unroll
        for (int ni = 0; ni < 4; ++ni)
#pragma unroll
            for (int kt = 0; kt < 4; ++kt) {
                int col = bcol + ni * 16 + (lane & 15);
                int ko = kh * 128 + kt * 32 + (lane >> 4) * 8;
                bfr[ni][kt] = *(const f16x8*)(Bw + (size_t)col * KTOT + ko);
            }
#pragma unroll
        for (int mi = 0; mi < 4; ++mi) {
            int rl = wm * 64 + mi * 16 + (lane & 15);
            const char* base = &sA[rl * ROWB + kh * 256 + (lane >> 4) * 16];
            f16x8 afr[4];
#pragma unroll
            for (int kt = 0; kt < 4; ++kt) afr[kt] = *(const f16x8*)(base + kt * 64);
#pragma unroll
            for (int kt = 0; kt < 4; ++kt)
#pragma unroll
                for (int ni = 0; ni < 4; ++ni)
                    acc[mi][ni] = __builtin_amdgcn_mfma_f32_16x16x32_f16(
                        afr[kt], bfr[ni][kt], acc[mi][ni], 0, 0, 0);
        }
    }

#pragma unroll
    for (int ni = 0; ni < 4; ++ni) {
        int col = bcol + ni * 16 + (lane & 15);
        float bv = bias[col];
        float gs = 0.f, bes = 0.f;
        if (BN_RELU) {
            gs = g[col] / sqrtf(1.0f + kBnEps);
            bes = be[col];
        }
#pragma unroll
        for (int mi = 0; mi < 4; ++mi) {
#pragma unroll
            for (int r = 0; r < 4; ++r) {
                int row = row0 + wm * 64 + mi * 16 + (lane >> 4) * 4 + r;
                if (row < n) {
                    float v = acc[mi][ni][r] + bv;
                    if (BN_RELU) v = fmaxf(v * gs + bes, 0.f);
                    if (OUT16)
                        ((__half*)outv)[(size_t)row * 128 + col] = __float2half_rn(v);
                    else
                        ((float*)outv)[(size_t)row * 128 + col] = v;
                }
            }
        }
    }
}

// ---------------------------------------------------------------------------
// Tiny head: out[N,7] = h2 @ dW2.T + db2 (h2 fp16, weights fp32 in LDS)
// ---------------------------------------------------------------------------
__global__ __launch_bounds__(256) void head2_k(const __half* __restrict__ h,
                                               const float* __restrict__ W2,
                                               const float* __restrict__ b2,
                                               float* __restrict__ out, int n) {
    __shared__ float sw[7 * 128];
    __shared__ float sb[7];
    int tid = threadIdx.x;
    for (int i = tid; i < 7 * 128; i += 256) sw[i] = W2[i];
    if (tid < 7) sb[tid] = b2[tid];
    __syncthreads();
    int row = blockIdx.x * 256 + tid;
    if (row >= n) return;
    const uint4* hr = (const uint4*)(h + (size_t)row * 128);
    float acc[7] = {0.f, 0.f, 0.f, 0.f, 0.f, 0.f, 0.f};
    for (int q = 0; q < 16; ++q) {
        uint4 u = hr[q];
        const __half2* p = (const __half2*)&u;
        float f[8];
#pragma unroll
        for (int t = 0; t < 4; ++t) {
            f[2 * t] = __low2float(p[t]);
            f[2 * t + 1] = __high2float(p[t]);
        }
#pragma unroll
        for (int c = 0; c < 7; ++c)
#pragma unroll
            for (int j = 0; j < 8; ++j) acc[c] += f[j] * sw[c * 128 + q * 8 + j];
    }
#pragma unroll
    for (int c = 0; c < 7; ++c) out[(size_t)row * 7 + c] = acc[c] + sb[c];
}

// ---------------------------------------------------------------------------
extern "C" void kernel_launch(void* const* d_in, const int* in_sizes, int n_in,
                              void* d_out, int out_size, void* d_ws, size_t ws_size,
                              hipStream_t stream) {
    const float* x   = (const float*)d_in[0];
    const int*   eb  = (const int*)d_in[1];
    const float* Wl0 = (const float*)d_in[2];
    const float* Wr0 = (const float*)d_in[3];
    const float* b0  = (const float*)d_in[4];
    const float* Wl1 = (const float*)d_in[5];
    const float* Wr1 = (const float*)d_in[6];
    const float* b1  = (const float*)d_in[7];
    const float* Wl2 = (const float*)d_in[8];
    const float* Wr2 = (const float*)d_in[9];
    const float* b2  = (const float*)d_in[10];
    const float* g0  = (const float*)d_in[11];
    const float* be0 = (const float*)d_in[12];
    const float* g1  = (const float*)d_in[13];
    const float* be1 = (const float*)d_in[14];
    const float* dW1 = (const float*)d_in[15];
    const float* db1 = (const float*)d_in[16];
    const float* dW2 = (const float*)d_in[17];
    const float* db2 = (const float*)d_in[18];
    const float* dW3 = (const float*)d_in[19];
    const float* db3 = (const float*)d_in[20];

    const int n = in_sizes[0] / 128;
    const int E = in_sizes[1] / 2;
    const int nbuck = (n + 127) >> 7;

    char* ws = (char*)d_ws;
    size_t off = 0;
    auto alloc = [&](size_t bytes) -> void* {
        void* p = ws + off;
        off = (off + bytes + 255) & ~(size_t)255;
        return p;
    };
    int*      flag  = (int*)alloc(16);
    int*      gcnt  = (int*)alloc(MAXB * 4);
    int*      gbase = (int*)alloc((MAXB + 1) * 4);
    int*      gcur  = (int*)alloc(MAXB * 4);
    unsigned* bins  = (unsigned*)alloc((size_t)E * 4);
    int*      csr   = (int*)alloc((size_t)E * 4);
    int*      offs  = (int*)alloc((size_t)(n + 1) * 4);
    __half*   x_h   = (__half*)alloc((size_t)n * 128 * 2);
    __half*   agg_h = (__half*)alloc((size_t)n * 128 * 2);
    __half*   h0    = (__half*)alloc((size_t)n * 128 * 2);
    __half*   h1    = (__half*)alloc((size_t)n * 128 * 2);
    __half*   h2    = h0;  // h0 dead after layer-1 gemm
    __half*   Wcat  = (__half*)alloc(3 * 32768 * 2);
    __half*   dWcat = (__half*)alloc(32768 * 2);

    float* out0 = (float*)d_out;
    float* out1 = out0 + (size_t)n * 128;
    float* out2 = out1 + (size_t)n * 7;

    hipMemsetAsync(gcnt, 0, MAXB * 4, stream);

    const int nbN = (n + 255) / 256;
    const int ggrid = (n + 127) / 128;
    const int agg_grid = (n * 64 + 255) / 256;
    const int chunk_grid = (E + 4095) / 4096;

    detect_k<<<1, 64, 0, stream>>>(eb, flag);
    histA_k<<<chunk_grid, 256, 0, stream>>>(eb, flag, gcnt, E, nbuck);
    scanB_k<<<1, 512, 0, stream>>>(gcnt, gbase, gcur, offs, E, n, nbuck);
    binC_k<<<chunk_grid, 256, 0, stream>>>(eb, flag, gcur, bins, E, nbuck);
    csrD_k<<<nbuck, 256, 0, stream>>>(bins, gbase, offs, csr, n);

    cvtx_k<<<(n * 16 + 255) / 256, 256, 0, stream>>>(x, x_h, n * 16);
    cvtw_k<<<(131072 + 255) / 256, 256, 0, stream>>>(Wl0, Wr0, Wl1, Wr1, Wl2, Wr2,
                                                     dW1, dW3, Wcat, dWcat);

    // layer 0
    agg_k<<<agg_grid, 256, 0, stream>>>(x_h, offs, csr, agg_h, n);
    mgemm_k<256, true, true, true><<<ggrid, 256, 0, stream>>>(
        agg_h, x_h, Wcat, b0, g0, be0, h0, nullptr, nullptr, n);
    // layer 1
    agg_k<<<agg_grid, 256, 0, stream>>>(h0, offs, csr, agg_h, n);
    mgemm_k<256, true, true, true><<<ggrid, 256, 0, stream>>>(
        agg_h, h0, Wcat + 32768, b1, g1, be1, h1, nullptr, nullptr, n);
    // layer 2 (no bn/relu); h2 aliases h0
    agg_k<<<agg_grid, 256, 0, stream>>>(h1, offs, csr, agg_h, n);
    mgemm_k<256, true, false, true><<<ggrid, 256, 0, stream>>>(
        agg_h, h1, Wcat + 65536, b2, nullptr, nullptr, h2, nullptr, nullptr, n);
    // fused heads
    mgemm_k<128, false, false, false><<<dim3(ggrid, 2), 256, 0, stream>>>(
        h2, nullptr, dWcat, db1, nullptr, nullptr, out0, db3, out2, n);
    head2_k<<<nbN, 256, 0, stream>>>(h2, dW2, db2, out1, n);
}